// Round 1
// baseline (276.769 us; speedup 1.0000x reference)
//
#include <hip/hip_runtime.h>
#include <hip/hip_bf16.h>

#define IN_DIM 8192
#define OUT_DIM 4096
#define CHUNKS 256
#define RPB 16                 // rows per chunk = OUT_DIM / CHUNKS
#define IN4 (IN_DIM / 4)       // 2048 float4 per row

constexpr float ALPHA = 0.001f;
constexpr float GAMMA = 0.99f;

// ---------------------------------------------------------------------------
// K1: fused matvec + per-chunk weighted partial sums.
// grid = CHUNKS blocks, 1024 threads. Each block owns 16 rows.
// Per row: load row into regs (2 float4/thread), dot with x (LDS),
// block-reduce -> pre, r2 = relu(pre)^2, accumulate q += r2 * w.
// Writes: r2buf[4096], chunkmax[256], q[CHUNKS][IN_DIM].
// ---------------------------------------------------------------------------
__global__ __launch_bounds__(1024)
void k1_matvec_partials(const float* __restrict__ x,
                        const float* __restrict__ W,
                        float* __restrict__ r2buf,
                        float* __restrict__ chunkmax,
                        float* __restrict__ q)
{
    __shared__ float sx[IN_DIM];     // 32 KB
    __shared__ float red[16];

    const int t = threadIdx.x;
    const int c = blockIdx.x;
    const int lane = t & 63;
    const int wid = t >> 6;

    // stage x into LDS (2 float4 per thread)
    float4* sx4 = (float4*)sx;
    const float4* x4 = (const float4*)x;
    sx4[t] = x4[t];
    sx4[t + 1024] = x4[t + 1024];
    __syncthreads();

    const float4 xa = sx4[t];
    const float4 xb = sx4[t + 1024];

    float4 acc0 = make_float4(0.f, 0.f, 0.f, 0.f);
    float4 acc1 = make_float4(0.f, 0.f, 0.f, 0.f);
    float maxr = 0.f;

    for (int rr = 0; rr < RPB; ++rr) {
        const int row = c * RPB + rr;
        const float4* wrow4 = (const float4*)(W + (size_t)row * IN_DIM);
        const float4 w0 = wrow4[t];
        const float4 w1 = wrow4[t + 1024];

        float local = w0.x * xa.x + w0.y * xa.y + w0.z * xa.z + w0.w * xa.w
                    + w1.x * xb.x + w1.y * xb.y + w1.z * xb.z + w1.w * xb.w;

        // 64-lane wave reduce
        for (int off = 32; off; off >>= 1) local += __shfl_down(local, off);
        if (lane == 0) red[wid] = local;
        __syncthreads();

        float pre = 0.f;
        #pragma unroll
        for (int i = 0; i < 16; ++i) pre += red[i];
        __syncthreads();   // protect red[] before next row's writes

        const float r  = pre > 0.f ? pre : 0.f;
        const float r2 = r * r;
        maxr = fmaxf(maxr, r);
        if (t == 0) r2buf[row] = r2;

        acc0.x += r2 * w0.x; acc0.y += r2 * w0.y;
        acc0.z += r2 * w0.z; acc0.w += r2 * w0.w;
        acc1.x += r2 * w1.x; acc1.y += r2 * w1.y;
        acc1.z += r2 * w1.z; acc1.w += r2 * w1.w;
    }

    if (t == 0) chunkmax[c] = maxr;

    float4* q4 = (float4*)(q + (size_t)c * IN_DIM);
    q4[t] = acc0;
    q4[t + 1024] = acc1;
}

// ---------------------------------------------------------------------------
// K2: global max -> inv = 1/max^2; y = r2*inv; new_exp_avg.
// grid = OUT_DIM/1024 blocks x 1024 threads (each block redundantly reduces
// the 256 chunk maxes -- trivial cost).
// ---------------------------------------------------------------------------
__global__ __launch_bounds__(1024)
void k2_y_expavg(const float* __restrict__ r2buf,
                 const float* __restrict__ chunkmax,
                 const float* __restrict__ exp_avg,
                 float* __restrict__ y_out,
                 float* __restrict__ exp_out,
                 float* __restrict__ invbuf)
{
    __shared__ float sm[16];
    const int t = threadIdx.x;
    const int lane = t & 63;
    const int wid = t >> 6;

    float v = (t < CHUNKS) ? chunkmax[t] : 0.f;
    for (int off = 32; off; off >>= 1) v = fmaxf(v, __shfl_down(v, off));
    if (lane == 0) sm[wid] = v;
    __syncthreads();
    float m = 0.f;
    #pragma unroll
    for (int i = 0; i < 16; ++i) m = fmaxf(m, sm[i]);

    const float inv = 1.f / (m * m);

    const int i = blockIdx.x * 1024 + t;
    const float yv = r2buf[i] * inv;
    y_out[i] = yv;
    exp_out[i] = GAMMA * exp_avg[i] + (1.f - GAMMA) * yv;

    if (blockIdx.x == 0 && t == 0) invbuf[0] = inv;
}

// ---------------------------------------------------------------------------
// K3: in-place exclusive scan of q over the chunk axis, per column.
// grid = IN_DIM/256 blocks x 256 threads; thread owns one column.
// Batched 8-wide so loads are issued together (q is L2/L3 resident).
// ---------------------------------------------------------------------------
__global__ __launch_bounds__(256)
void k3_chunk_scan(float* __restrict__ q)
{
    const int j = blockIdx.x * 256 + threadIdx.x;
    float s = 0.f;
    for (int cc = 0; cc < CHUNKS; cc += 8) {
        float v[8];
        #pragma unroll
        for (int u = 0; u < 8; ++u) v[u] = q[(size_t)(cc + u) * IN_DIM + j];
        #pragma unroll
        for (int u = 0; u < 8; ++u) { const float tmp = v[u]; v[u] = s; s += tmp; }
        #pragma unroll
        for (int u = 0; u < 8; ++u) q[(size_t)(cc + u) * IN_DIM + j] = v[u];
    }
}

// ---------------------------------------------------------------------------
// K4: apply update. grid = (8 col-tiles, 256 chunks), 256 threads.
// Thread owns 4 consecutive columns (float4); runs the inclusive scan over
// its chunk's 16 rows starting from the exclusive chunk prefix, and writes
// new_W = w + ALPHA * y[l] * (x[j] - inv * s).
// ---------------------------------------------------------------------------
__global__ __launch_bounds__(256)
void k4_apply(const float* __restrict__ x,
              const float* __restrict__ W,
              const float* __restrict__ r2buf,
              const float* __restrict__ q,       // exclusive chunk prefix (q-units)
              const float* __restrict__ invbuf,
              float* __restrict__ newW)
{
    __shared__ float sr2[RPB];
    __shared__ float sinv;

    const int c = blockIdx.y;
    const int tile = blockIdx.x;
    const int t = threadIdx.x;

    if (t < RPB) sr2[t] = r2buf[c * RPB + t];
    if (t == RPB) sinv = invbuf[0];
    __syncthreads();
    const float inv = sinv;

    const int j4 = tile * 256 + t;              // float4 column index
    const float4 xv = ((const float4*)x)[j4];
    float4 s = ((const float4*)q)[(size_t)c * IN4 + j4];

    #pragma unroll
    for (int rr = 0; rr < RPB; ++rr) {
        const int row = c * RPB + rr;
        const float4 w = ((const float4*)W)[(size_t)row * IN4 + j4];
        const float r2 = sr2[rr];
        s.x += r2 * w.x; s.y += r2 * w.y; s.z += r2 * w.z; s.w += r2 * w.w;
        const float yl = inv * r2;
        const float a  = ALPHA * yl;
        float4 o;
        o.x = w.x + a * (xv.x - inv * s.x);
        o.y = w.y + a * (xv.y - inv * s.y);
        o.z = w.z + a * (xv.z - inv * s.z);
        o.w = w.w + a * (xv.w - inv * s.w);
        ((float4*)newW)[(size_t)row * IN4 + j4] = o;
    }
}

// ---------------------------------------------------------------------------
extern "C" void kernel_launch(void* const* d_in, const int* in_sizes, int n_in,
                              void* d_out, int out_size, void* d_ws, size_t ws_size,
                              hipStream_t stream)
{
    const float* x       = (const float*)d_in[0];
    const float* W       = (const float*)d_in[1];
    const float* exp_avg = (const float*)d_in[2];

    float* y_out   = (float*)d_out;                                   // [4096]
    float* newW    = (float*)d_out + OUT_DIM;                         // [4096*8192]
    float* exp_out = (float*)d_out + OUT_DIM + (size_t)OUT_DIM * IN_DIM; // [4096]

    // workspace layout (floats)
    float* ws       = (float*)d_ws;
    float* q        = ws;                                   // CHUNKS*IN_DIM = 2M floats
    float* r2buf    = ws + (size_t)CHUNKS * IN_DIM;         // 4096
    float* chunkmax = r2buf + OUT_DIM;                      // 256
    float* invbuf   = chunkmax + CHUNKS;                    // 1

    k1_matvec_partials<<<CHUNKS, 1024, 0, stream>>>(x, W, r2buf, chunkmax, q);
    k2_y_expavg<<<OUT_DIM / 1024, 1024, 0, stream>>>(r2buf, chunkmax, exp_avg,
                                                     y_out, exp_out, invbuf);
    k3_chunk_scan<<<IN_DIM / 256, 256, 0, stream>>>(q);
    k4_apply<<<dim3(IN_DIM / 1024, CHUNKS), 256, 0, stream>>>(x, W, r2buf, q,
                                                              invbuf, newW);
}

// Round 6
// 274.733 us; speedup vs baseline: 1.0074x; 1.0074x over previous
//
#include <hip/hip_runtime.h>
#include <hip/hip_bf16.h>

#define IN_DIM 8192
#define OUT_DIM 4096
#define CHUNKS 256
#define RPB 16                 // rows per chunk = OUT_DIM / CHUNKS
#define IN4 (IN_DIM / 4)       // 2048 float4 per row
#define BATCH 4                // rows per reduce phase in K1

#define SCAN_COLS 32           // columns per block in the fused scan
#define SCAN_SEGS 8            // segments over the chunk axis
#define SEG_LEN (CHUNKS / SCAN_SEGS)   // 32

constexpr float ALPHA = 0.001f;
constexpr float GAMMA = 0.99f;

typedef float f32x4 __attribute__((ext_vector_type(4)));

// ---------------------------------------------------------------------------
// K1: fused matvec + per-chunk weighted partial sums.
// grid = CHUNKS blocks x 1024 threads; block owns 16 rows, batched 4 at a
// time: load 4 rows (8 float4 in flight/thread), wave-reduce 4 dots,
// wave-specialized cross-wave reduce, then accumulate q += r2*w from regs.
// chunkmax stores max of r^2 (monotonic in r, so fine for the global max).
// ---------------------------------------------------------------------------
__global__ __launch_bounds__(1024)
void k1_matvec_partials(const float* __restrict__ x,
                        const float* __restrict__ W,
                        float* __restrict__ r2buf,
                        float* __restrict__ chunkmax,
                        float* __restrict__ q)
{
    __shared__ float sx[IN_DIM];          // 32 KB
    __shared__ float red[BATCH][16];
    __shared__ float sr2[RPB];

    const int t = threadIdx.x;
    const int c = blockIdx.x;
    const int lane = t & 63;
    const int wid = t >> 6;

    float4* sx4 = (float4*)sx;
    sx4[t] = ((const float4*)x)[t];
    sx4[t + 1024] = ((const float4*)x)[t + 1024];
    __syncthreads();
    const float4 xa = sx4[t];
    const float4 xb = sx4[t + 1024];

    float4 acc0 = make_float4(0.f, 0.f, 0.f, 0.f);
    float4 acc1 = make_float4(0.f, 0.f, 0.f, 0.f);

    for (int bb = 0; bb < RPB / BATCH; ++bb) {
        const int rb = c * RPB + bb * BATCH;

        float4 w0[BATCH], w1[BATCH];
        #pragma unroll
        for (int r = 0; r < BATCH; ++r) {
            const float4* row4 = (const float4*)(W + (size_t)(rb + r) * IN_DIM);
            w0[r] = row4[t];
            w1[r] = row4[t + 1024];
        }

        #pragma unroll
        for (int r = 0; r < BATCH; ++r) {
            float d = w0[r].x * xa.x + w0[r].y * xa.y + w0[r].z * xa.z + w0[r].w * xa.w
                    + w1[r].x * xb.x + w1[r].y * xb.y + w1[r].z * xb.z + w1[r].w * xb.w;
            for (int off = 32; off; off >>= 1) d += __shfl_down(d, off);
            if (lane == 0) red[r][wid] = d;
        }
        __syncthreads();

        // waves 0..BATCH-1 each finish one row
        if (wid < BATCH) {
            float v = (lane < 16) ? red[wid][lane] : 0.f;
            for (int off = 8; off; off >>= 1) v += __shfl_down(v, off);
            if (lane == 0) {
                const float rr = v > 0.f ? v : 0.f;
                const float r2 = rr * rr;
                sr2[bb * BATCH + wid] = r2;
                r2buf[rb + wid] = r2;
            }
        }
        __syncthreads();

        #pragma unroll
        for (int r = 0; r < BATCH; ++r) {
            const float r2 = sr2[bb * BATCH + r];
            acc0.x += r2 * w0[r].x; acc0.y += r2 * w0[r].y;
            acc0.z += r2 * w0[r].z; acc0.w += r2 * w0[r].w;
            acc1.x += r2 * w1[r].x; acc1.y += r2 * w1[r].y;
            acc1.z += r2 * w1[r].z; acc1.w += r2 * w1[r].w;
        }
    }

    if (t == 0) {
        float m = 0.f;
        #pragma unroll
        for (int i = 0; i < RPB; ++i) m = fmaxf(m, sr2[i]);
        chunkmax[c] = m;                  // max of r^2
    }

    float4* q4 = (float4*)(q + (size_t)c * IN_DIM);
    q4[t] = acc0;
    q4[t + 1024] = acc1;
}

// ---------------------------------------------------------------------------
// K2 (fused): global max -> inv = 1/max(r^2); y + new_exp_avg; and the
// per-column exclusive scan of q over the 256 chunks.
// grid = 256 blocks x 256 threads. Block b: columns [b*32, b*32+32),
// 8 segments x 32 chunks each; two-phase scan (seg sums -> LDS seg scan ->
// rewrite exclusive values).
// ---------------------------------------------------------------------------
__global__ __launch_bounds__(256)
void k2_fused(const float* __restrict__ r2buf,
              const float* __restrict__ chunkmax,
              const float* __restrict__ exp_avg,
              float* __restrict__ y_out,
              float* __restrict__ exp_out,
              float* __restrict__ invbuf,
              float* __restrict__ q)
{
    __shared__ float sred[4];
    __shared__ float sinv;
    __shared__ float segsum[SCAN_SEGS][SCAN_COLS];

    const int t = threadIdx.x;
    const int b = blockIdx.x;
    const int lane = t & 63;
    const int wid = t >> 6;

    // global max over the 256 chunk maxima (every block redundantly)
    float v = chunkmax[t];
    for (int off = 32; off; off >>= 1) v = fmaxf(v, __shfl_down(v, off));
    if (lane == 0) sred[wid] = v;
    __syncthreads();
    if (t == 0) {
        const float m = fmaxf(fmaxf(sred[0], sred[1]), fmaxf(sred[2], sred[3]));
        sinv = 1.f / m;                   // m is max(r)^2
    }
    __syncthreads();
    const float inv = sinv;

    // y and new_exp_avg: 16 rows per block
    if (t < 16) {
        const int i = b * 16 + t;
        const float yv = r2buf[i] * inv;
        y_out[i] = yv;
        exp_out[i] = GAMMA * exp_avg[i] + (1.f - GAMMA) * yv;
    }
    if (b == 0 && t == 0) invbuf[0] = inv;

    // exclusive scan of q over the chunk axis
    const int col = t & (SCAN_COLS - 1);
    const int seg = t >> 5;
    const int j = b * SCAN_COLS + col;

    float s = 0.f;
    #pragma unroll 8
    for (int u = 0; u < SEG_LEN; ++u)
        s += q[(size_t)(seg * SEG_LEN + u) * IN_DIM + j];
    segsum[seg][col] = s;
    __syncthreads();

    float off_ = 0.f;
    #pragma unroll
    for (int s2 = 0; s2 < SCAN_SEGS; ++s2)
        if (s2 < seg) off_ += segsum[s2][col];

    float run = off_;
    #pragma unroll 8
    for (int u = 0; u < SEG_LEN; ++u) {
        const size_t idx = (size_t)(seg * SEG_LEN + u) * IN_DIM + j;
        const float val = q[idx];
        q[idx] = run;
        run += val;
    }
}

// ---------------------------------------------------------------------------
// K4: apply update. grid = (8 col-tiles, 256 chunks) x 256 threads.
// All 16 W loads issued before the serial scan chain; newW written with
// nontemporal stores so the write stream doesn't evict W from L2/L3.
// ---------------------------------------------------------------------------
__global__ __launch_bounds__(256)
void k4_apply(const float* __restrict__ x,
              const float* __restrict__ W,
              const float* __restrict__ r2buf,
              const float* __restrict__ q,       // exclusive chunk prefix
              const float* __restrict__ invbuf,
              float* __restrict__ newW)
{
    __shared__ float sr2[RPB];
    __shared__ float sinv;

    const int c = blockIdx.y;
    const int tile = blockIdx.x;
    const int t = threadIdx.x;

    if (t < RPB) sr2[t] = r2buf[c * RPB + t];
    if (t == RPB) sinv = invbuf[0];
    __syncthreads();
    const float inv = sinv;

    const int j4 = tile * 256 + t;                // float4 column index
    const float4 xv = ((const float4*)x)[j4];
    float4 s = ((const float4*)q)[(size_t)c * IN4 + j4];

    float4 w[RPB];
    #pragma unroll
    for (int rr = 0; rr < RPB; ++rr)
        w[rr] = ((const float4*)W)[(size_t)(c * RPB + rr) * IN4 + j4];

    #pragma unroll
    for (int rr = 0; rr < RPB; ++rr) {
        const float r2 = sr2[rr];
        s.x += r2 * w[rr].x; s.y += r2 * w[rr].y;
        s.z += r2 * w[rr].z; s.w += r2 * w[rr].w;
        const float a = ALPHA * inv * r2;
        f32x4 o;
        o.x = w[rr].x + a * (xv.x - inv * s.x);
        o.y = w[rr].y + a * (xv.y - inv * s.y);
        o.z = w[rr].z + a * (xv.z - inv * s.z);
        o.w = w[rr].w + a * (xv.w - inv * s.w);
        __builtin_nontemporal_store(o, (f32x4*)(newW + (size_t)(c * RPB + rr) * IN_DIM) + j4);
    }
}

// ---------------------------------------------------------------------------
extern "C" void kernel_launch(void* const* d_in, const int* in_sizes, int n_in,
                              void* d_out, int out_size, void* d_ws, size_t ws_size,
                              hipStream_t stream)
{
    const float* x       = (const float*)d_in[0];
    const float* W       = (const float*)d_in[1];
    const float* exp_avg = (const float*)d_in[2];

    float* y_out   = (float*)d_out;                                      // [4096]
    float* newW    = (float*)d_out + OUT_DIM;                            // [4096*8192]
    float* exp_out = (float*)d_out + OUT_DIM + (size_t)OUT_DIM * IN_DIM; // [4096]

    float* ws       = (float*)d_ws;
    float* q        = ws;                                   // CHUNKS*IN_DIM floats
    float* r2buf    = ws + (size_t)CHUNKS * IN_DIM;         // 4096
    float* chunkmax = r2buf + OUT_DIM;                      // 256
    float* invbuf   = chunkmax + CHUNKS;                    // 1

    k1_matvec_partials<<<CHUNKS, 1024, 0, stream>>>(x, W, r2buf, chunkmax, q);
    k2_fused<<<IN_DIM / SCAN_COLS, 256, 0, stream>>>(r2buf, chunkmax, exp_avg,
                                                     y_out, exp_out, invbuf, q);
    k4_apply<<<dim3(IN_DIM / 1024, CHUNKS), 256, 0, stream>>>(x, W, r2buf, q,
                                                              invbuf, newW);
}